// Round 6
// baseline (136.525 us; speedup 1.0000x reference)
//
#include <hip/hip_runtime.h>

// Problem dims (from reference setup_inputs)
#define BB 4
#define CC 64
#define HH 256
#define WW 256
#define NPIX (HH*WW)          // 65536
#define NCLS 4
#define NPAIR 12              // B*(NCLS-1)
#define HALF 512
#define MAXS 1024
#define NOUT (NPAIR*CC*MAXS)  // 786432
#define CHUNK 4096
#define NCHUNK (NPIX/CHUNK)   // 16
#define NBAND 64              // 4-row bands per image
#define CPG 4                 // channels per gather block

// ---------------------------------------------------------------------------
// K1: fused argmax + separable 3x3 dilation + per-band hard/easy counting.
// (verified absmax=0 in round 5; unchanged)
// ---------------------------------------------------------------------------
__global__ void __launch_bounds__(256) k_dargmax(
        const float* __restrict__ preds, const int* __restrict__ labels,
        unsigned char* __restrict__ pd, unsigned* __restrict__ bandCounts) {
    __shared__ unsigned char vm[4][WW];
    __shared__ unsigned wsum[4][3];
    int bx = blockIdx.x;
    int b = bx >> 6, band = bx & 63;
    int y0 = band * 4;
    int x = threadIdx.x;
    const float* pb = preds + (size_t)b * NCLS * NPIX;

    unsigned char am[6];
#pragma unroll
    for (int r = 0; r < 6; ++r) {
        int y = y0 + r - 1;
        unsigned char a = 0;
        if (y >= 0 && y < HH) {
            const float* p = pb + y * WW + x;
            float best = p[0];
            int arg = 0;
#pragma unroll
            for (int c = 1; c < NCLS; ++c) {
                float v = p[(size_t)c * NPIX];
                if (v > best) { best = v; arg = c; }   // first-max wins (jnp.argmax)
            }
            a = (unsigned char)arg;
        }
        am[r] = a;
    }
    unsigned char vmr[4];
#pragma unroll
    for (int ry = 0; ry < 4; ++ry) {
        int m = am[ry];
        if (am[ry + 1] > m) m = am[ry + 1];
        if (am[ry + 2] > m) m = am[ry + 2];
        vmr[ry] = (unsigned char)m;
        vm[ry][x] = (unsigned char)m;
    }
    __syncthreads();

    unsigned pk[3] = {0u, 0u, 0u};
#pragma unroll
    for (int ry = 0; ry < 4; ++ry) {
        int m = vmr[ry];
        if (x > 0)      { int v = vm[ry][x - 1]; if (v > m) m = v; }
        if (x < WW - 1) { int v = vm[ry][x + 1]; if (v > m) m = v; }
        int idx = b * NPIX + (y0 + ry) * WW + x;
        pd[idx] = (unsigned char)m;
        int l = labels[idx];
#pragma unroll
        for (int c = 0; c < 3; ++c)
            if (l == c + 1) pk[c] += (m == c + 1) ? (1u << 16) : 1u;
    }
    int lane = x & 63, w = x >> 6;
#pragma unroll
    for (int c = 0; c < 3; ++c)
#pragma unroll
        for (int off = 32; off > 0; off >>= 1)
            pk[c] += (unsigned)__shfl_down((int)pk[c], off, 64);
    if (lane == 0) { wsum[w][0] = pk[0]; wsum[w][1] = pk[1]; wsum[w][2] = pk[2]; }
    __syncthreads();
    if (x < 3)
        bandCounts[(b * 3 + x) * NBAND + band] =
            wsum[0][x] + wsum[1][x] + wsum[2][x] + wsum[3][x];
}

// ---------------------------------------------------------------------------
// K2: fused slot-assignment + gather. Grid = 192 blocks: pair = bx>>4,
// channel group oc = bx&15 (4 channels). Each block redundantly rebuilds its
// pair's full slot table in LDS -- cheap, because the per-chunk base ranks
// come closed-form from the band counts (no carry chain) and only chunks that
// can land a pixel in slot<1024 are compacted (typically 2-4 of 16). Then it
// gathers its 4 channels with slots read from LDS. The global slots[] buffer
// and one kernel launch are eliminated.
//  hard rank r  -> slot r                 (if r < 1024)
//  easy rank e  -> slot 512 + excess + e  (if < 1024), excess = max(Nh-512,0)
// ---------------------------------------------------------------------------
__global__ void __launch_bounds__(256) k_asgather(
        const int* __restrict__ labels, const unsigned char* __restrict__ pd,
        const unsigned* __restrict__ bandCounts, const float* __restrict__ feat,
        float* __restrict__ out) {
    int pair = blockIdx.x >> 4, oc = blockIdx.x & 15;
    int b = pair / 3, cls = pair % 3 + 1;
    int t = threadIdx.x;
    int lane = t & 63, w = t >> 6;

    __shared__ int sl[MAXS];
    __shared__ unsigned bcs[NBAND];
    __shared__ unsigned ws[4];
#pragma unroll
    for (int j = 0; j < 4; ++j) sl[t + j * 256] = -1;
    if (t < NBAND) bcs[t] = bandCounts[pair * NBAND + t];
    __syncthreads();

    // redundant per-thread (LDS broadcast reads): total + per-chunk prefix
    unsigned total = 0;
#pragma unroll
    for (int i = 0; i < NBAND; ++i) total += bcs[i];
    int excess = (int)(total & 0xffffu) - HALF;
    if (excess < 0) excess = 0;
    if (oc == 0 && t == 0) out[NOUT + pair] = (float)cls;   // feat_label

    unsigned runBase = 0;
#pragma unroll
    for (int ch = 0; ch < NCHUNK; ++ch) {
        unsigned myBase = runBase;
        runBase += bcs[4 * ch] + bcs[4 * ch + 1] + bcs[4 * ch + 2] + bcs[4 * ch + 3];
        int baseH = (int)(myBase & 0xffffu), baseE = (int)(myBase >> 16);
        if (baseH >= MAXS && HALF + excess + baseE >= MAXS) continue;  // uniform skip

        const int4* lab4 = (const int4*)(labels + b * NPIX + ch * CHUNK + t * 16);
        const uint4* pd16 = (const uint4*)(pd + b * NPIX + ch * CHUNK + t * 16);
        int4 l0 = lab4[0], l1 = lab4[1], l2 = lab4[2], l3 = lab4[3];
        uint4 dp = pd16[0];
        int ls[16] = {l0.x, l0.y, l0.z, l0.w, l1.x, l1.y, l1.z, l1.w,
                      l2.x, l2.y, l2.z, l2.w, l3.x, l3.y, l3.z, l3.w};
        unsigned char ds[16];
        unsigned dw[4] = {dp.x, dp.y, dp.z, dp.w};
#pragma unroll
        for (int j = 0; j < 16; ++j) ds[j] = (dw[j >> 2] >> ((j & 3) * 8)) & 0xff;

        unsigned mine = 0;
#pragma unroll
        for (int j = 0; j < 16; ++j)
            if (ls[j] == cls) mine += (ds[j] == cls) ? (1u << 16) : 1u;

        unsigned v = mine;
#pragma unroll
        for (int off = 1; off < 64; off <<= 1) {
            unsigned u = (unsigned)__shfl_up((int)v, off, 64);
            if (lane >= off) v += u;
        }
        if (lane == 63) ws[w] = v;
        __syncthreads();
        unsigned waveBase = 0;
        for (int i = 0; i < w; ++i) waveBase += ws[i];
        unsigned excl = waveBase + v - mine;

        int hr = baseH + (int)(excl & 0xffffu);
        int er = baseE + (int)(excl >> 16);
        int pixBase = ch * CHUNK + t * 16;
#pragma unroll
        for (int j = 0; j < 16; ++j) {
            if (ls[j] == cls) {
                if (ds[j] != cls) {
                    if (hr < MAXS) sl[hr] = pixBase + j;
                    hr++;
                } else {
                    int pos = HALF + excess + er;
                    if (pos < MAXS) sl[pos] = pixBase + j;
                    er++;
                }
            }
        }
        __syncthreads();   // sl writes visible; ws safe for next round
    }
    __syncthreads();

    // gather: 4 channels x 1024 slots; thread t -> slots 4t..4t+3 (float4 store)
    int slot = t * 4;
    int p0 = sl[slot], p1 = sl[slot + 1], p2 = sl[slot + 2], p3 = sl[slot + 3];
    const float* fb = feat + ((size_t)(b * CC + oc * CPG)) * NPIX;
    float* ob = out + (size_t)pair * CC * MAXS + (size_t)(oc * CPG) * MAXS + slot;
#pragma unroll
    for (int c = 0; c < CPG; ++c) {
        const float* fp = fb + (size_t)c * NPIX;
        float4 o;
        o.x = (p0 >= 0) ? fp[p0] : 0.0f;
        o.y = (p1 >= 0) ? fp[p1] : 0.0f;
        o.z = (p2 >= 0) ? fp[p2] : 0.0f;
        o.w = (p3 >= 0) ? fp[p3] : 0.0f;
        *(float4*)(ob + c * MAXS) = o;
    }
}

extern "C" void kernel_launch(void* const* d_in, const int* in_sizes, int n_in,
                              void* d_out, int out_size, void* d_ws, size_t ws_size,
                              hipStream_t stream) {
    const float* feat   = (const float*)d_in[0];  // [B,C,H,W] fp32
    const int*   labels = (const int*)d_in[1];    // [B,H,W] int32
    const float* preds  = (const float*)d_in[2];  // [B,NCLS,H,W] fp32
    float* out = (float*)d_out;

    unsigned char* pd = (unsigned char*)d_ws;                 // 262144 B
    unsigned* bandCounts = (unsigned*)(pd + BB * NPIX);       // 768 uints

    k_dargmax<<<NBAND * BB, 256, 0, stream>>>(preds, labels, pd, bandCounts);
    k_asgather<<<NPAIR * NCHUNK, 256, 0, stream>>>(labels, pd, bandCounts, feat, out);
}